// Round 13
// baseline (255.238 us; speedup 1.0000x reference)
//
#include <hip/hip_runtime.h>
#include <stdint.h>

#define IN1 16
#define HIDC 10
#define OUT3 16
#define NTYPES 25
#define MAXB 8
#define NBUCK 32  // degree buckets for node binning
#define HSTR 12   // padded row stride (floats) for h1/h2: 48B, 16B-aligned rows

#define D1 (IN1 * HIDC)    // 160
#define D2 (HIDC * HIDC)   // 100
#define D3 (HIDC * OUT3)   // 160

// ---------------- init: prep P tables + zero deg/psum/pcnt/bcnt --------------
// w_edge = relu(f0*P0 + f1*P1 + P2); P0=emb*wh0+wg0, P1=emb*wh1+wg1, P2=emb*bh+bg
__global__ __launch_bounds__(256) void init_kernel(
    const float* __restrict__ emb1, const float* __restrict__ wh1,
    const float* __restrict__ bh1, const float* __restrict__ wg1,
    const float* __restrict__ bg1,
    const float* __restrict__ emb2, const float* __restrict__ wh2,
    const float* __restrict__ bh2, const float* __restrict__ wg2,
    const float* __restrict__ bg2,
    const float* __restrict__ emb3, const float* __restrict__ wh3,
    const float* __restrict__ bh3, const float* __restrict__ wg3,
    const float* __restrict__ bg3,
    float4* __restrict__ P1, float4* __restrict__ P2, float4* __restrict__ P3,
    int* __restrict__ deg, int N,
    float* __restrict__ psum, float* __restrict__ pcnt,
    int* __restrict__ bcnt, int B)
{
  int gtid = blockIdx.x * 256 + threadIdx.x;
  int gstr = gridDim.x * 256;
  const int nPrep = NTYPES * (D1 + D2 + D3);
  for (int i = gtid; i < nPrep; i += gstr) {
    const float *emb, *wh, *bh, *wg, *bg; float4* P; int D, k;
    if (i < NTYPES * D1) {
      emb = emb1; wh = wh1; bh = bh1; wg = wg1; bg = bg1; P = P1; D = D1; k = i;
    } else if (i < NTYPES * (D1 + D2)) {
      emb = emb2; wh = wh2; bh = bh2; wg = wg2; bg = bg2; P = P2; D = D2;
      k = i - NTYPES * D1;
    } else {
      emb = emb3; wh = wh3; bh = bh3; wg = wg3; bg = bg3; P = P3; D = D3;
      k = i - NTYPES * (D1 + D2);
    }
    int j = k - (k / D) * D;
    float e = emb[k];
    float4 p;
    p.x = fmaf(e, wh[j],     wg[j]);
    p.y = fmaf(e, wh[D + j], wg[D + j]);
    p.z = fmaf(e, bh[j],     bg[j]);
    p.w = 0.f;
    P[k] = p;
  }
  for (int i = gtid; i < N; i += gstr) deg[i] = 0;
  for (int i = gtid; i < B * 16; i += gstr) psum[i] = 0.f;
  for (int i = gtid; i < B; i += gstr) pcnt[i] = 0.f;
  if (gtid < NBUCK) bcnt[gtid] = 0;
}

// ---------------- histogram + within-bucket rank (1 atomic per edge) ----------
__global__ __launch_bounds__(256) void hist_kernel(const int* __restrict__ edst,
                                                   int* __restrict__ deg,
                                                   int* __restrict__ pos, int E) {
  int e = blockIdx.x * blockDim.x + threadIdx.x;
  if (e < E) pos[e] = atomicAdd(&deg[edst[e]], 1);
}

// ---------------- per-1024-chunk local scan + chunk sum + degree buckets -----
__global__ __launch_bounds__(256) void scan_part_kernel(const int* __restrict__ deg,
                                                        int* __restrict__ row_ptr,
                                                        int* __restrict__ bsum,
                                                        int* __restrict__ bcnt, int N) {
  __shared__ int wsums[4];
  __shared__ int s_cnt[NBUCK];
  int tid = threadIdx.x, lane = tid & 63, wid = tid >> 6;
  if (tid < NBUCK) s_cnt[tid] = 0;
  int idx0 = (blockIdx.x * 256 + tid) * 4;
  int4 v = make_int4(0, 0, 0, 0);
  if (idx0 < N)     v.x = deg[idx0];
  if (idx0 + 1 < N) v.y = deg[idx0 + 1];
  if (idx0 + 2 < N) v.z = deg[idx0 + 2];
  if (idx0 + 3 < N) v.w = deg[idx0 + 3];
  __syncthreads();   // s_cnt zero visible
  if (idx0 < N)     atomicAdd(&s_cnt[min(v.x, NBUCK - 1)], 1);
  if (idx0 + 1 < N) atomicAdd(&s_cnt[min(v.y, NBUCK - 1)], 1);
  if (idx0 + 2 < N) atomicAdd(&s_cnt[min(v.z, NBUCK - 1)], 1);
  if (idx0 + 3 < N) atomicAdd(&s_cnt[min(v.w, NBUCK - 1)], 1);
  int s = v.x + v.y + v.z + v.w;
  int x = s;
  #pragma unroll
  for (int off = 1; off < 64; off <<= 1) {
    int y = __shfl_up(x, off);
    if (lane >= off) x += y;
  }
  if (lane == 63) wsums[wid] = x;
  __syncthreads();
  int wpre = 0;
  #pragma unroll
  for (int w = 0; w < 4; ++w) if (w < wid) wpre += wsums[w];
  int excl = x - s + wpre;
  if (idx0 < N)     row_ptr[idx0]     = excl;
  if (idx0 + 1 < N) row_ptr[idx0 + 1] = excl + v.x;
  if (idx0 + 2 < N) row_ptr[idx0 + 2] = excl + v.x + v.y;
  if (idx0 + 3 < N) row_ptr[idx0 + 3] = excl + v.x + v.y + v.z;
  if (tid == 255) bsum[blockIdx.x] = excl + s;
  __syncthreads();   // all s_cnt adds done
  if (tid < NBUCK && s_cnt[tid] > 0) atomicAdd(&bcnt[tid], s_cnt[tid]);
}

// ---------------- fused chunk-offset scan + add; block 0 scans buckets -------
__global__ __launch_bounds__(256) void scan_add2_kernel(int* __restrict__ row_ptr,
                                                        const int* __restrict__ bsum,
                                                        const int* __restrict__ bcnt,
                                                        int* __restrict__ boff,
                                                        int N, int chunks) {
  __shared__ int s_off;
  int c = blockIdx.x, tid = threadIdx.x;
  if (tid < 64) {
    int v = (tid < c) ? bsum[tid] : 0;
    #pragma unroll
    for (int off = 32; off >= 1; off >>= 1) v += __shfl_xor(v, off);
    if (tid == 0) s_off = v;
  }
  if (c == 0 && tid >= 64 && tid < 128) {   // wave 1: exclusive scan of bcnt
    int l = tid - 64;
    int b = (l < NBUCK) ? bcnt[l] : 0;
    int x = b;
    #pragma unroll
    for (int off = 1; off < NBUCK; off <<= 1) {
      int y = __shfl_up(x, off);
      if (l >= off) x += y;
    }
    if (l < NBUCK) boff[l] = x - b;
  }
  __syncthreads();
  int off = s_off;
  int base = c * 1024 + tid * 4;
  #pragma unroll
  for (int j = 0; j < 4; ++j) {
    int idx = base + j;
    if (idx < N) row_ptr[idx] += off;
  }
  if (c == chunks - 1 && tid == 0) row_ptr[N] = off + bsum[c];
}

// ---------------- assign: counting-sort nodes by degree into order[] ---------
__global__ __launch_bounds__(256) void assign_kernel(const int* __restrict__ deg,
                                                     int* __restrict__ boff,
                                                     int* __restrict__ order, int N) {
  __shared__ int s_cnt[NBUCK];
  __shared__ int s_base[NBUCK];
  int tid = threadIdx.x;
  if (tid < NBUCK) s_cnt[tid] = 0;
  __syncthreads();
  int n = blockIdx.x * 256 + tid;
  int b = 0, lr = 0;
  if (n < N) {
    b = min(deg[n], NBUCK - 1);
    lr = atomicAdd(&s_cnt[b], 1);
  }
  __syncthreads();
  if (tid < NBUCK && s_cnt[tid] > 0) s_base[tid] = atomicAdd(&boff[tid], s_cnt[tid]);
  __syncthreads();
  if (n < N) order[s_base[b] + lr] = n;
}

// ---------------- scatter edges into CSR order (plain stores) ----------------
__global__ __launch_bounds__(256) void permute_kernel(
    const int* __restrict__ edst, const int* __restrict__ esrc,
    const int* __restrict__ et, const float2* __restrict__ ef,
    const int* __restrict__ row_ptr, const int* __restrict__ pos,
    int4* __restrict__ edges, int E) {
  int e = blockIdx.x * blockDim.x + threadIdx.x;
  if (e >= E) return;
  int d = edst[e];
  int idx = row_ptr[d] + pos[e];
  float2 f = ef[e];
  int4 r;
  r.x = esrc[e];
  r.y = et[e];
  r.z = __float_as_int(f.x);
  r.w = __float_as_int(f.y);
  edges[idx] = r;
}

// ---------------- fused gather layer (R8 inner loop + degree-sorted order) ---
// Per (i,oc): 1 broadcast ds_read_b128 of packed {P0,P1,P2} + 4 VALU.
// Nodes processed in degree-sorted order via order[]: the 4 node-groups of a
// wave have near-equal degrees -> max(deg)~mean -> ~37% fewer wave-iterations.
template<int IN_C, int O, int XS, bool POOL, int BS>
__global__ __launch_bounds__(BS) void layer_kernel(
    const float* __restrict__ xin, const int4* __restrict__ edges,
    const int* __restrict__ row_ptr, const int* __restrict__ order,
    const float4* __restrict__ Pg,
    const float* __restrict__ root, const float* __restrict__ bias,
    float* __restrict__ hout, const int* __restrict__ ctype,
    const int* __restrict__ bids, float* __restrict__ pcnt, int N, int B)
{
  constexpr int D = IN_C * O;
  constexpr int TSTR = D + 1;
  constexpr int NPB = BS / 16;
  __shared__ float4 s_P[NTYPES * TSTR];
  __shared__ float s_psum[POOL ? (MAXB * 16) : 1];
  __shared__ float s_pcnt[POOL ? MAXB : 1];

  int tid = threadIdx.x;
  for (int k = tid; k < NTYPES * D; k += BS) {
    int t = k / D, j = k - t * D;
    s_P[t * TSTR + j] = Pg[k];
  }
  if (POOL) {
    for (int i = tid; i < MAXB * 16; i += BS) s_psum[i] = 0.f;
    for (int i = tid; i < MAXB; i += BS) s_pcnt[i] = 0.f;
  }
  __syncthreads();

  int nl = tid >> 4;
  int o = tid & 15;
  int oc = (O == 16) ? o : ((o < O) ? o : 0);
  int idx = blockIdx.x * NPB + nl;
  int n = (idx < N) ? order[idx] : N;

  float acc = 0.f;
  int start = 0, end = 0;
  if (n < N) { start = row_ptr[n]; end = row_ptr[n + 1]; }
  for (int e = start; e < end; ++e) {
    int4 r = edges[e];
    float f0 = __int_as_float(r.z), f1 = __int_as_float(r.w);
    const float4* __restrict__ pb = s_P + r.y * TSTR + oc;
    const float* __restrict__ xr = xin + (size_t)r.x * XS;
    #pragma unroll
    for (int q = 0; q < IN_C / 4; ++q) {
      float4 xq = ((const float4*)xr)[q];
      float4 p0 = pb[(4 * q + 0) * O];
      float4 p1 = pb[(4 * q + 1) * O];
      float4 p2 = pb[(4 * q + 2) * O];
      float4 p3 = pb[(4 * q + 3) * O];
      acc = fmaf(xq.x, fmaxf(fmaf(f0, p0.x, fmaf(f1, p0.y, p0.z)), 0.f), acc);
      acc = fmaf(xq.y, fmaxf(fmaf(f0, p1.x, fmaf(f1, p1.y, p1.z)), 0.f), acc);
      acc = fmaf(xq.z, fmaxf(fmaf(f0, p2.x, fmaf(f1, p2.y, p2.z)), 0.f), acc);
      acc = fmaf(xq.w, fmaxf(fmaf(f0, p3.x, fmaf(f1, p3.y, p3.z)), 0.f), acc);
    }
    if constexpr (IN_C % 4 == 2) {
      float2 xq = ((const float2*)xr)[IN_C / 2 - 1];
      float4 p0 = pb[(IN_C - 2) * O];
      float4 p1 = pb[(IN_C - 1) * O];
      acc = fmaf(xq.x, fmaxf(fmaf(f0, p0.x, fmaf(f1, p0.y, p0.z)), 0.f), acc);
      acc = fmaf(xq.y, fmaxf(fmaf(f0, p1.x, fmaf(f1, p1.y, p1.z)), 0.f), acc);
    }
  }

  if (n < N && o < O) {
    float inv = 1.0f / fmaxf((float)(end - start), 1.0f);
    float v = fmaf(acc, inv, bias[o]);
    const float* __restrict__ xr = xin + (size_t)n * XS;
    #pragma unroll
    for (int i = 0; i < IN_C; ++i) v = fmaf(xr[i], root[i * O + o], v);
    v = fmaxf(v, 0.f);
    if (!POOL) {
      hout[(size_t)n * HSTR + o] = v;
    } else {
      if (ctype[n] == 1) {
        int b = bids[n];
        atomicAdd(&s_psum[b * 16 + o], v);
        if (o == 0) atomicAdd(&s_pcnt[b], 1.0f);
      }
    }
  }

  if (POOL) {
    __syncthreads();
    for (int i = tid; i < B * 16; i += BS) {
      float v = s_psum[i];
      if (v != 0.f) atomicAdd(&hout[i], v);
    }
    for (int i = tid; i < B; i += BS) {
      float c = s_pcnt[i];
      if (c != 0.f) atomicAdd(&pcnt[i], c);
    }
  }
}

__global__ __launch_bounds__(256) void finalize_kernel(
    const float* __restrict__ psum, const float* __restrict__ pcnt,
    float* __restrict__ out, int B) {
  int i = blockIdx.x * blockDim.x + threadIdx.x;
  if (i >= B * OUT3) return;
  int b = i / OUT3;
  out[i] = psum[i] / fmaxf(pcnt[b], 1.0f);
}

// ---------------- launch ----------------
extern "C" void kernel_launch(void* const* d_in, const int* in_sizes, int n_in,
                              void* d_out, int out_size, void* d_ws, size_t ws_size,
                              hipStream_t stream)
{
  const float* x     = (const float*)d_in[0];
  const float* ef    = (const float*)d_in[1];
  const int*   et    = (const int*)d_in[2];
  const int*   esrc  = (const int*)d_in[3];
  const int*   edst  = (const int*)d_in[4];
  const int*   ctype = (const int*)d_in[5];
  const int*   bids  = (const int*)d_in[6];
  const float* emb1 = (const float*)d_in[8];
  const float* wh1  = (const float*)d_in[9];
  const float* bh1  = (const float*)d_in[10];
  const float* wg1  = (const float*)d_in[11];
  const float* bg1  = (const float*)d_in[12];
  const float* root1= (const float*)d_in[13];
  const float* bias1= (const float*)d_in[14];
  const float* emb2 = (const float*)d_in[15];
  const float* wh2  = (const float*)d_in[16];
  const float* bh2  = (const float*)d_in[17];
  const float* wg2  = (const float*)d_in[18];
  const float* bg2  = (const float*)d_in[19];
  const float* root2= (const float*)d_in[20];
  const float* bias2= (const float*)d_in[21];
  const float* emb3 = (const float*)d_in[22];
  const float* wh3  = (const float*)d_in[23];
  const float* bh3  = (const float*)d_in[24];
  const float* wg3  = (const float*)d_in[25];
  const float* bg3  = (const float*)d_in[26];
  const float* root3= (const float*)d_in[27];
  const float* bias3= (const float*)d_in[28];

  const int N = in_sizes[0] / IN1;
  const int E = in_sizes[2];
  const int B = out_size / OUT3;

  // workspace layout (16B-aligned sections)
  int4* edges   = (int4*)d_ws;                       // E recs
  int*  deg     = (int*)(edges + E);                 // N
  int*  pos     = deg + N;                           // E
  int*  row_ptr = pos + E;                           // N+1
  int*  bsum    = row_ptr + (N + 1);                 // <=64
  int*  bcnt    = bsum + 64;                         // 32
  int*  boff    = bcnt + NBUCK;                      // 32
  int*  order   = boff + NBUCK;                      // N
  uintptr_t pp  = ((uintptr_t)(order + N) + 15) & ~(uintptr_t)15;
  float4* P1    = (float4*)pp;                       // 25*D1
  float4* P2    = P1 + NTYPES * D1;                  // 25*D2
  float4* P3    = P2 + NTYPES * D2;                  // 25*D3
  float* h1     = (float*)(P3 + NTYPES * D3);        // N*HSTR
  float* h2     = h1 + (size_t)N * HSTR;             // N*HSTR
  float* psum   = h2 + (size_t)N * HSTR;             // B*16
  float* pcnt   = psum + (size_t)B * 16;             // B

  const int nChunk = (N + 1023) / 1024;

  init_kernel<<<128, 256, 0, stream>>>(
      emb1, wh1, bh1, wg1, bg1, emb2, wh2, bh2, wg2, bg2,
      emb3, wh3, bh3, wg3, bg3, P1, P2, P3, deg, N, psum, pcnt, bcnt, B);
  hist_kernel<<<(E + 255) / 256, 256, 0, stream>>>(edst, deg, pos, E);
  scan_part_kernel<<<nChunk, 256, 0, stream>>>(deg, row_ptr, bsum, bcnt, N);
  scan_add2_kernel<<<nChunk, 256, 0, stream>>>(row_ptr, bsum, bcnt, boff, N, nChunk);
  assign_kernel<<<(N + 255) / 256, 256, 0, stream>>>(deg, boff, order, N);
  permute_kernel<<<(E + 255) / 256, 256, 0, stream>>>(
      edst, esrc, et, (const float2*)ef, row_ptr, pos, edges, E);

  const int g512 = (N + 31) / 32;     // 32 nodes per 512-thread block
  layer_kernel<IN1, HIDC, IN1, false, 512><<<g512, 512, 0, stream>>>(
      x, edges, row_ptr, order, P1, root1, bias1,
      h1, nullptr, nullptr, nullptr, N, B);
  layer_kernel<HIDC, HIDC, HSTR, false, 512><<<g512, 512, 0, stream>>>(
      h1, edges, row_ptr, order, P2, root2, bias2,
      h2, nullptr, nullptr, nullptr, N, B);

  const int g1024 = (N + 63) / 64;    // 64 nodes per 1024-thread block
  layer_kernel<HIDC, OUT3, HSTR, true, 1024><<<g1024, 1024, 0, stream>>>(
      h2, edges, row_ptr, order, P3, root3, bias3,
      psum, ctype, bids, pcnt, N, B);

  finalize_kernel<<<1, 256, 0, stream>>>(psum, pcnt, (float*)d_out, B);
}

// Round 14
// 252.269 us; speedup vs baseline: 1.0118x; 1.0118x over previous
//
#include <hip/hip_runtime.h>
#include <stdint.h>

#define IN1 16
#define HIDC 10
#define OUT3 16
#define NTYPES 25
#define MAXB 8
#define HSTR 12   // padded row stride (floats) for h1/h2: 48B, 16B-aligned rows

#define D1 (IN1 * HIDC)    // 160
#define D2 (HIDC * HIDC)   // 100
#define D3 (HIDC * OUT3)   // 160

// ---------------- init: prep P tables + zero deg/psum/pcnt -------------------
// w_edge = relu(f0*P0 + f1*P1 + P2); P0=emb*wh0+wg0, P1=emb*wh1+wg1, P2=emb*bh+bg
__global__ __launch_bounds__(256) void init_kernel(
    const float* __restrict__ emb1, const float* __restrict__ wh1,
    const float* __restrict__ bh1, const float* __restrict__ wg1,
    const float* __restrict__ bg1,
    const float* __restrict__ emb2, const float* __restrict__ wh2,
    const float* __restrict__ bh2, const float* __restrict__ wg2,
    const float* __restrict__ bg2,
    const float* __restrict__ emb3, const float* __restrict__ wh3,
    const float* __restrict__ bh3, const float* __restrict__ wg3,
    const float* __restrict__ bg3,
    float4* __restrict__ P1, float4* __restrict__ P2, float4* __restrict__ P3,
    int* __restrict__ deg, int N,
    float* __restrict__ psum, float* __restrict__ pcnt, int B)
{
  int gtid = blockIdx.x * 256 + threadIdx.x;
  int gstr = gridDim.x * 256;
  const int nPrep = NTYPES * (D1 + D2 + D3);
  for (int i = gtid; i < nPrep; i += gstr) {
    const float *emb, *wh, *bh, *wg, *bg; float4* P; int D, k;
    if (i < NTYPES * D1) {
      emb = emb1; wh = wh1; bh = bh1; wg = wg1; bg = bg1; P = P1; D = D1; k = i;
    } else if (i < NTYPES * (D1 + D2)) {
      emb = emb2; wh = wh2; bh = bh2; wg = wg2; bg = bg2; P = P2; D = D2;
      k = i - NTYPES * D1;
    } else {
      emb = emb3; wh = wh3; bh = bh3; wg = wg3; bg = bg3; P = P3; D = D3;
      k = i - NTYPES * (D1 + D2);
    }
    int j = k - (k / D) * D;
    float e = emb[k];
    float4 p;
    p.x = fmaf(e, wh[j],     wg[j]);
    p.y = fmaf(e, wh[D + j], wg[D + j]);
    p.z = fmaf(e, bh[j],     bg[j]);
    p.w = 0.f;
    P[k] = p;
  }
  for (int i = gtid; i < N; i += gstr) deg[i] = 0;
  for (int i = gtid; i < B * 16; i += gstr) psum[i] = 0.f;
  for (int i = gtid; i < B; i += gstr) pcnt[i] = 0.f;
}

// ---------------- histogram + within-bucket rank (1 atomic per edge) ----------
__global__ __launch_bounds__(256) void hist_kernel(const int* __restrict__ edst,
                                                   int* __restrict__ deg,
                                                   int* __restrict__ pos, int E) {
  int e = blockIdx.x * blockDim.x + threadIdx.x;
  if (e < E) pos[e] = atomicAdd(&deg[edst[e]], 1);
}

// ---------------- per-1024-chunk local scan + chunk sum ----------------------
__global__ __launch_bounds__(256) void scan_part_kernel(const int* __restrict__ deg,
                                                        int* __restrict__ row_ptr,
                                                        int* __restrict__ bsum, int N) {
  __shared__ int wsums[4];
  int tid = threadIdx.x, lane = tid & 63, wid = tid >> 6;
  int idx0 = (blockIdx.x * 256 + tid) * 4;
  int4 v = make_int4(0, 0, 0, 0);
  if (idx0 < N)     v.x = deg[idx0];
  if (idx0 + 1 < N) v.y = deg[idx0 + 1];
  if (idx0 + 2 < N) v.z = deg[idx0 + 2];
  if (idx0 + 3 < N) v.w = deg[idx0 + 3];
  int s = v.x + v.y + v.z + v.w;
  int x = s;
  #pragma unroll
  for (int off = 1; off < 64; off <<= 1) {
    int y = __shfl_up(x, off);
    if (lane >= off) x += y;
  }
  if (lane == 63) wsums[wid] = x;
  __syncthreads();
  int wpre = 0;
  #pragma unroll
  for (int w = 0; w < 4; ++w) if (w < wid) wpre += wsums[w];
  int excl = x - s + wpre;
  if (idx0 < N)     row_ptr[idx0]     = excl;
  if (idx0 + 1 < N) row_ptr[idx0 + 1] = excl + v.x;
  if (idx0 + 2 < N) row_ptr[idx0 + 2] = excl + v.x + v.y;
  if (idx0 + 3 < N) row_ptr[idx0 + 3] = excl + v.x + v.y + v.z;
  if (tid == 255) bsum[blockIdx.x] = excl + s;
}

// ---------------- fused chunk-offset scan + add (chunks <= 64) ----------------
__global__ __launch_bounds__(256) void scan_add2_kernel(int* __restrict__ row_ptr,
                                                        const int* __restrict__ bsum,
                                                        int N, int chunks) {
  __shared__ int s_off;
  int c = blockIdx.x, tid = threadIdx.x;
  if (tid < 64) {
    int v = (tid < c) ? bsum[tid] : 0;
    #pragma unroll
    for (int off = 32; off >= 1; off >>= 1) v += __shfl_xor(v, off);
    if (tid == 0) s_off = v;
  }
  __syncthreads();
  int off = s_off;
  int base = c * 1024 + tid * 4;
  #pragma unroll
  for (int j = 0; j < 4; ++j) {
    int idx = base + j;
    if (idx < N) row_ptr[idx] += off;
  }
  if (c == chunks - 1 && tid == 0) row_ptr[N] = off + bsum[c];
}

// ---------------- scatter edges into CSR order (plain stores) ----------------
__global__ __launch_bounds__(256) void permute_kernel(
    const int* __restrict__ edst, const int* __restrict__ esrc,
    const int* __restrict__ et, const float2* __restrict__ ef,
    const int* __restrict__ row_ptr, const int* __restrict__ pos,
    int4* __restrict__ edges, int E) {
  int e = blockIdx.x * blockDim.x + threadIdx.x;
  if (e >= E) return;
  int d = edst[e];
  int idx = row_ptr[d] + pos[e];
  float2 f = ef[e];
  int4 r;
  r.x = esrc[e];
  r.y = et[e];
  r.z = __float_as_int(f.x);
  r.w = __float_as_int(f.y);
  edges[idx] = r;
}

// ---------------- fused gather layer: edge-slot-parallel decomposition -------
// wave = 1 node x 4 edge-slots x 16 output-lanes (lane = es*16 + o).
// Each wave processes 4 CONSECUTIVE nodes serially (natural order -> CSR/x
// locality kept); within a node, edge-slot es takes edges start+es, +4, ...
//  - 4x memory-level parallelism on the x[src] gather (4 rows in flight in
//    one load instruction) vs the old serial per-node edge loop
//  - divergence waste E[4*ceil(d/4)-d]/d ~ 23% vs 37% for max-of-4-nodes
//  - cross-slot reduce: 2 shfl_xor; per-node acc stashed in its es-slot so
//    all 4 epilogues run in one pass with all 64 lanes useful
// Inner math/preamble/LDS layout byte-identical to R8 (regalloc-safe).
template<int IN_C, int O, int XS, bool POOL, int BS>
__global__ __launch_bounds__(BS) void layer_kernel(
    const float* __restrict__ xin, const int4* __restrict__ edges,
    const int* __restrict__ row_ptr, const float4* __restrict__ Pg,
    const float* __restrict__ root, const float* __restrict__ bias,
    float* __restrict__ hout, const int* __restrict__ ctype,
    const int* __restrict__ bids, float* __restrict__ pcnt, int N, int B)
{
  constexpr int D = IN_C * O;
  constexpr int TSTR = D + 1;
  constexpr int NPW = 4;                 // nodes per wave (serial)
  constexpr int NPB = (BS / 64) * NPW;   // nodes per block
  __shared__ float4 s_P[NTYPES * TSTR];
  __shared__ float s_psum[POOL ? (MAXB * 16) : 1];
  __shared__ float s_pcnt[POOL ? MAXB : 1];

  int tid = threadIdx.x;
  for (int k = tid; k < NTYPES * D; k += BS) {
    int t = k / D, j = k - t * D;
    s_P[t * TSTR + j] = Pg[k];
  }
  if (POOL) {
    for (int i = tid; i < MAXB * 16; i += BS) s_psum[i] = 0.f;
    for (int i = tid; i < MAXB; i += BS) s_pcnt[i] = 0.f;
  }
  __syncthreads();

  int lane = tid & 63;
  int wv = tid >> 6;
  int o = lane & 15;
  int es = lane >> 4;                    // edge slot 0..3
  int oc = (O == 16) ? o : ((o < O) ? o : 0);
  int nb = (blockIdx.x * (BS / 64) + wv) * NPW;

  float accs = 0.f;                      // my es-slot's node acc
  int degs = 0;

  #pragma unroll
  for (int s = 0; s < NPW; ++s) {
    int n = nb + s;
    float acc = 0.f;
    int start = 0, end = 0;
    if (n < N) { start = row_ptr[n]; end = row_ptr[n + 1]; }
    for (int e = start + es; e < end; e += 4) {
      int4 r = edges[e];
      float f0 = __int_as_float(r.z), f1 = __int_as_float(r.w);
      const float4* __restrict__ pb = s_P + r.y * TSTR + oc;
      const float* __restrict__ xr = xin + (size_t)r.x * XS;
      #pragma unroll
      for (int q = 0; q < IN_C / 4; ++q) {
        float4 xq = ((const float4*)xr)[q];
        float4 p0 = pb[(4 * q + 0) * O];
        float4 p1 = pb[(4 * q + 1) * O];
        float4 p2 = pb[(4 * q + 2) * O];
        float4 p3 = pb[(4 * q + 3) * O];
        acc = fmaf(xq.x, fmaxf(fmaf(f0, p0.x, fmaf(f1, p0.y, p0.z)), 0.f), acc);
        acc = fmaf(xq.y, fmaxf(fmaf(f0, p1.x, fmaf(f1, p1.y, p1.z)), 0.f), acc);
        acc = fmaf(xq.z, fmaxf(fmaf(f0, p2.x, fmaf(f1, p2.y, p2.z)), 0.f), acc);
        acc = fmaf(xq.w, fmaxf(fmaf(f0, p3.x, fmaf(f1, p3.y, p3.z)), 0.f), acc);
      }
      if constexpr (IN_C % 4 == 2) {
        float2 xq = ((const float2*)xr)[IN_C / 2 - 1];
        float4 p0 = pb[(IN_C - 2) * O];
        float4 p1 = pb[(IN_C - 1) * O];
        acc = fmaf(xq.x, fmaxf(fmaf(f0, p0.x, fmaf(f1, p0.y, p0.z)), 0.f), acc);
        acc = fmaf(xq.y, fmaxf(fmaf(f0, p1.x, fmaf(f1, p1.y, p1.z)), 0.f), acc);
      }
    }
    // reduce over edge slots (o preserved)
    acc += __shfl_xor(acc, 16);
    acc += __shfl_xor(acc, 32);
    if (es == s) { accs = acc; degs = end - start; }
  }

  // parallel epilogue: es-group handles node nb+es
  int n = nb + es;
  if (n < N && o < O) {
    float inv = 1.0f / fmaxf((float)degs, 1.0f);
    float v = fmaf(accs, inv, bias[o]);
    const float* __restrict__ xr = xin + (size_t)n * XS;
    #pragma unroll
    for (int i = 0; i < IN_C; ++i) v = fmaf(xr[i], root[i * O + o], v);
    v = fmaxf(v, 0.f);
    if (!POOL) {
      hout[(size_t)n * HSTR + o] = v;
    } else {
      if (ctype[n] == 1) {
        int b = bids[n];
        atomicAdd(&s_psum[b * 16 + o], v);
        if (o == 0) atomicAdd(&s_pcnt[b], 1.0f);
      }
    }
  }

  if (POOL) {
    __syncthreads();
    for (int i = tid; i < B * 16; i += BS) {
      float v = s_psum[i];
      if (v != 0.f) atomicAdd(&hout[i], v);
    }
    for (int i = tid; i < B; i += BS) {
      float c = s_pcnt[i];
      if (c != 0.f) atomicAdd(&pcnt[i], c);
    }
  }
}

__global__ __launch_bounds__(256) void finalize_kernel(
    const float* __restrict__ psum, const float* __restrict__ pcnt,
    float* __restrict__ out, int B) {
  int i = blockIdx.x * blockDim.x + threadIdx.x;
  if (i >= B * OUT3) return;
  int b = i / OUT3;
  out[i] = psum[i] / fmaxf(pcnt[b], 1.0f);
}

// ---------------- launch ----------------
extern "C" void kernel_launch(void* const* d_in, const int* in_sizes, int n_in,
                              void* d_out, int out_size, void* d_ws, size_t ws_size,
                              hipStream_t stream)
{
  const float* x     = (const float*)d_in[0];
  const float* ef    = (const float*)d_in[1];
  const int*   et    = (const int*)d_in[2];
  const int*   esrc  = (const int*)d_in[3];
  const int*   edst  = (const int*)d_in[4];
  const int*   ctype = (const int*)d_in[5];
  const int*   bids  = (const int*)d_in[6];
  const float* emb1 = (const float*)d_in[8];
  const float* wh1  = (const float*)d_in[9];
  const float* bh1  = (const float*)d_in[10];
  const float* wg1  = (const float*)d_in[11];
  const float* bg1  = (const float*)d_in[12];
  const float* root1= (const float*)d_in[13];
  const float* bias1= (const float*)d_in[14];
  const float* emb2 = (const float*)d_in[15];
  const float* wh2  = (const float*)d_in[16];
  const float* bh2  = (const float*)d_in[17];
  const float* wg2  = (const float*)d_in[18];
  const float* bg2  = (const float*)d_in[19];
  const float* root2= (const float*)d_in[20];
  const float* bias2= (const float*)d_in[21];
  const float* emb3 = (const float*)d_in[22];
  const float* wh3  = (const float*)d_in[23];
  const float* bh3  = (const float*)d_in[24];
  const float* wg3  = (const float*)d_in[25];
  const float* bg3  = (const float*)d_in[26];
  const float* root3= (const float*)d_in[27];
  const float* bias3= (const float*)d_in[28];

  const int N = in_sizes[0] / IN1;
  const int E = in_sizes[2];
  const int B = out_size / OUT3;

  // workspace layout (16B-aligned sections)
  int4* edges   = (int4*)d_ws;                       // E recs
  int*  deg     = (int*)(edges + E);                 // N
  int*  pos     = deg + N;                           // E
  int*  row_ptr = pos + E;                           // N+1
  int*  bsum    = row_ptr + (N + 1);                 // <=64
  uintptr_t pp  = ((uintptr_t)(bsum + 64) + 15) & ~(uintptr_t)15;
  float4* P1    = (float4*)pp;                       // 25*D1
  float4* P2    = P1 + NTYPES * D1;                  // 25*D2
  float4* P3    = P2 + NTYPES * D2;                  // 25*D3
  float* h1     = (float*)(P3 + NTYPES * D3);        // N*HSTR
  float* h2     = h1 + (size_t)N * HSTR;             // N*HSTR
  float* psum   = h2 + (size_t)N * HSTR;             // B*16
  float* pcnt   = psum + (size_t)B * 16;             // B

  const int nChunk = (N + 1023) / 1024;

  init_kernel<<<128, 256, 0, stream>>>(
      emb1, wh1, bh1, wg1, bg1, emb2, wh2, bh2, wg2, bg2,
      emb3, wh3, bh3, wg3, bg3, P1, P2, P3, deg, N, psum, pcnt, B);
  hist_kernel<<<(E + 255) / 256, 256, 0, stream>>>(edst, deg, pos, E);
  scan_part_kernel<<<nChunk, 256, 0, stream>>>(deg, row_ptr, bsum, N);
  scan_add2_kernel<<<nChunk, 256, 0, stream>>>(row_ptr, bsum, N, nChunk);
  permute_kernel<<<(E + 255) / 256, 256, 0, stream>>>(
      edst, esrc, et, (const float2*)ef, row_ptr, pos, edges, E);

  const int g512 = (N + 31) / 32;     // 32 nodes per 512-thread block (8w x 4n)
  layer_kernel<IN1, HIDC, IN1, false, 512><<<g512, 512, 0, stream>>>(
      x, edges, row_ptr, P1, root1, bias1,
      h1, nullptr, nullptr, nullptr, N, B);
  layer_kernel<HIDC, HIDC, HSTR, false, 512><<<g512, 512, 0, stream>>>(
      h1, edges, row_ptr, P2, root2, bias2,
      h2, nullptr, nullptr, nullptr, N, B);

  const int g1024 = (N + 63) / 64;    // 64 nodes per 1024-thread block
  layer_kernel<HIDC, OUT3, HSTR, true, 1024><<<g1024, 1024, 0, stream>>>(
      h2, edges, row_ptr, P3, root3, bias3,
      psum, ctype, bids, pcnt, N, B);

  finalize_kernel<<<1, 256, 0, stream>>>(psum, pcnt, (float*)d_out, B);
}